// Round 3
// baseline (5781.735 us; speedup 1.0000x reference)
//
#include <hip/hip_runtime.h>

#define B_   32
#define S_   512
#define V_   768
#define H_   512
#define M_   (B_*S_)      // 16384 rows
#define NALL 5120         // 2048 fwd gates | 2048 bwd gates | 1024 skip
#define KV   768
#define RWG  32           // recurrence workgroups (16 per direction)

typedef __bf16 bf16;
typedef __bf16 bf16x8 __attribute__((ext_vector_type(8)));
typedef __bf16 bf16x4v __attribute__((ext_vector_type(4)));
typedef float  f32x4  __attribute__((ext_vector_type(4)));

__device__ __forceinline__ float sigm(float x)  { return 1.0f / (1.0f + __expf(-x)); }
// stable: no NaN at +-inf
__device__ __forceinline__ float tanh_(float x) { return 1.0f - 2.0f / (__expf(2.0f*x) + 1.0f); }

// device-scope (cross-XCD coherent via L3) accesses — no cache-wide fences needed
__device__ __forceinline__ unsigned long long ld_u64_dev(const unsigned long long* p) {
    return __hip_atomic_load(p, __ATOMIC_RELAXED, __HIP_MEMORY_SCOPE_AGENT);
}
__device__ __forceinline__ void st_b16_dev(bf16* p, bf16 v) {
    unsigned short u = __builtin_bit_cast(unsigned short, v);
    asm volatile("global_store_short %0, %1, off sc1" :: "v"((void*)p), "v"(u) : "memory");
}

// ---------------- prep: fp32 -> bf16 cast of values ----------------
__global__ void k_cvt_values(const float* __restrict__ v, bf16* __restrict__ o, int n) {
    int i = (blockIdx.x * blockDim.x + threadIdx.x) * 4;
    if (i < n) {
        float4 f = *(const float4*)(v + i);
        bf16x4v t;
        t[0] = (bf16)f.x; t[1] = (bf16)f.y; t[2] = (bf16)f.z; t[3] = (bf16)f.w;
        *(bf16x4v*)(o + i) = t;
    }
}

// ---------------- prep: alpha bitmask (alphas are exactly 0/1) ----------------
__global__ void k_prep_abit(const float* __restrict__ alphas, unsigned int* __restrict__ abit) {
    int i = blockIdx.x * blockDim.x + threadIdx.x;   // 512 threads: b=i>>4, w=i&15
    if (i >= 512) return;
    int b = i >> 4, w = i & 15;
    unsigned int m = 0;
    #pragma unroll
    for (int j = 0; j < 32; j++)
        if (alphas[b * S_ + w * 32 + j] != 0.f) m |= (1u << j);
    abit[b * 16 + w] = m;
}

// ---------------- prep: build transposed+interleaved weight cat ----------------
__global__ void k_prep_wcat(const float* __restrict__ Wx_f, const float* __restrict__ Wx_b,
                            const float* __restrict__ Ws,
                            const float* __restrict__ b_f, const float* __restrict__ b_b,
                            const float* __restrict__ bs,
                            bf16* __restrict__ wcat, float* __restrict__ biascat) {
    int idx = blockIdx.x * blockDim.x + threadIdx.x;   // 5120*96 threads
    int n = idx / 96, kc = idx % 96;
    if (n >= NALL) return;
    const float* src; int col, ldn;
    if (n < 4096) {
        int d = n >> 11, nl = n & 2047, unit = nl >> 2, gate = nl & 3;
        col = gate * H_ + unit; src = d ? Wx_b : Wx_f; ldn = 2048;
        if (kc == 0) biascat[n] = (d ? b_b : b_f)[col];
    } else {
        col = n - 4096; src = Ws; ldn = 1024;
        if (kc == 0) biascat[n] = bs[col];
    }
    int k0 = kc * 8;
    bf16x8 t;
    #pragma unroll
    for (int j = 0; j < 8; j++) t[j] = (bf16)src[(size_t)(k0 + j) * ldn + col];
    *(bf16x8*)(wcat + (size_t)n * KV + k0) = t;
}

// ---------------- prep: WhT (2 dirs x 2048 rows x 512 k), same interleave ----------------
__global__ void k_prep_wh(const float* __restrict__ Wh_f, const float* __restrict__ Wh_b,
                          bf16* __restrict__ whT) {
    int idx = blockIdx.x * blockDim.x + threadIdx.x;   // 4096*64 threads
    int n = idx >> 6, kc = idx & 63;
    if (n >= 4096) return;
    int d = n >> 11, nl = n & 2047, unit = nl >> 2, gate = nl & 3;
    int col = gate * H_ + unit;
    const float* src = d ? Wh_b : Wh_f;
    int k0 = kc * 8;
    bf16x8 t;
    #pragma unroll
    for (int j = 0; j < 8; j++) t[j] = (bf16)src[(size_t)(k0 + j) * 2048 + col];
    *(bf16x8*)(whT + (size_t)n * H_ + k0) = t;
}

// ---------------- big GEMM: XG[16384 x 5120] = vals_bf16 @ wcat^T + bias ----------------
#define BM 64
#define BN 64
#define BK 32
#define LDT 40

__launch_bounds__(256)
__global__ void k_gemm(const bf16* __restrict__ A, const bf16* __restrict__ Bw,
                       const float* __restrict__ bias, bf16* __restrict__ C) {
    __shared__ bf16 As[BM * LDT];
    __shared__ bf16 Bs[BN * LDT];
    int m0 = blockIdx.x * BM, n0 = blockIdx.y * BN;
    int tid = threadIdx.x;
    int wv = tid >> 6, lane = tid & 63, lm = lane & 15, q = lane >> 4;
    int wm = (wv >> 1) * 32, wn = (wv & 1) * 32;
    f32x4 acc[2][2] = {};
    int lr = tid >> 2, lc = (tid & 3) * 8;
    const bf16* Ag = A  + (size_t)(m0 + lr) * KV + lc;
    const bf16* Bg = Bw + (size_t)(n0 + lr) * KV + lc;
    for (int kb = 0; kb < KV; kb += BK) {
        *(bf16x8*)&As[lr * LDT + lc] = *(const bf16x8*)(Ag + kb);
        *(bf16x8*)&Bs[lr * LDT + lc] = *(const bf16x8*)(Bg + kb);
        __syncthreads();
        bf16x8 af[2], bfr[2];
        af[0]  = *(bf16x8*)&As[(wm      + lm) * LDT + q * 8];
        af[1]  = *(bf16x8*)&As[(wm + 16 + lm) * LDT + q * 8];
        bfr[0] = *(bf16x8*)&Bs[(wn      + lm) * LDT + q * 8];
        bfr[1] = *(bf16x8*)&Bs[(wn + 16 + lm) * LDT + q * 8];
        #pragma unroll
        for (int mt = 0; mt < 2; mt++)
            #pragma unroll
            for (int nt = 0; nt < 2; nt++)
                acc[mt][nt] = __builtin_amdgcn_mfma_f32_16x16x32_bf16(af[mt], bfr[nt], acc[mt][nt], 0, 0, 0);
        __syncthreads();
    }
    #pragma unroll
    for (int mt = 0; mt < 2; mt++)
        #pragma unroll
        for (int nt = 0; nt < 2; nt++) {
            int col = n0 + wn + nt * 16 + lm;
            float bv = bias[col];
            #pragma unroll
            for (int r = 0; r < 4; r++) {
                int row = m0 + wm + mt * 16 + q * 4 + r;
                C[(size_t)row * NALL + col] = (bf16)(acc[mt][nt][r] + bv);
            }
        }
}

// ---------------- recurrence: transposed MFMA, fence-free sc1 exchange ----------------
// 32 WGs: d=wg>>4, slice sl=wg&15 owns units [sl*32, sl*32+32) (128 gate cols).
// MFMA: A = Wh slice rows (gate cols, persistent in VGPRs), B = h rows (batches).
// C lane layout: gatecol m = wv*32+mt*16+q*4+r, batch n = nt*16+lm
//   -> r spans the 4 interleaved gates of unit u = wv*8+mt*4+q: all-in-register gates.
// c and h2 live in registers across steps (h2 reg is the frozen-state source).
// Exchange: h stores/loads are device-scope (sc1, L3-coherent); ordering via
// s_waitcnt vmcnt(0) + relaxed flag. No buffer_wbl2/buffer_inv anywhere.
__launch_bounds__(256, 1)
__global__ void k_rnn(const bf16* __restrict__ XG, const bf16* __restrict__ WhT,
                      const unsigned int* __restrict__ abit,
                      bf16* __restrict__ hex, int* __restrict__ flags,
                      bf16* __restrict__ outf, bf16* __restrict__ outb) {
    __shared__ unsigned int ab[32 * 16];
    int wg = blockIdx.x;
    int d = wg >> 4, sl = wg & 15;
    int tid = threadIdx.x;
    int wv = tid >> 6, lane = tid & 63, lm = lane & 15, q = lane >> 4;
    bf16* outp = d ? outb : outf;
    int* myflags = flags + d * 64;

    for (int i = tid; i < 512; i += 256) ab[i] = abit[i];

    // persistent Wh fragments: rows d*2048+sl*128+wv*32+{0,16}+lm, k-contig. 128 VGPRs.
    const bf16* wb = WhT + (size_t)(d * 2048 + sl * 128 + wv * 32 + lm) * H_ + q * 8;
    bf16x8 wr0[16], wr1[16];
    #pragma unroll
    for (int kt = 0; kt < 16; kt++) {
        wr0[kt] = *(const bf16x8*)(wb + kt * 32);
        wr1[kt] = *(const bf16x8*)(wb + (size_t)16 * H_ + kt * 32);
    }
    __syncthreads();

    int b0 = lm, b1 = 16 + lm;
    int u0 = sl * 32 + wv * 8 + q;      // global unit for mt=0; mt=1 is u0+4
    int xcb = d * 2048 + sl * 128 + wv * 32 + q * 4;
    float c00 = 0.f, c01 = 0.f, c10 = 0.f, c11 = 0.f;
    float h00 = 0.f, h01 = 0.f, h10 = 0.f, h11 = 0.f;

    for (int t = 0; t < S_; t++) {
        int s = d ? (S_ - 1 - t) : t;
        const bf16* hprev = hex + (size_t)(d * 2 + (t & 1)) * (32 * H_);
        bf16*       hnext = hex + (size_t)(d * 2 + ((t + 1) & 1)) * (32 * H_);

        // prefetch xg + alpha bits (independent of h) before the poll
        size_t r0 = (size_t)(b0 * S_ + s) * NALL + xcb;
        size_t r1 = (size_t)(b1 * S_ + s) * NALL + xcb;
        bf16x4v x00 = *(const bf16x4v*)(XG + r0);
        bf16x4v x01 = *(const bf16x4v*)(XG + r1);
        bf16x4v x10 = *(const bf16x4v*)(XG + r0 + 16);
        bf16x4v x11 = *(const bf16x4v*)(XG + r1 + 16);
        bool a0 = (ab[b0 * 16 + (s >> 5)] >> (s & 31)) & 1;
        bool a1 = (ab[b1 * 16 + (s >> 5)] >> (s & 31)) & 1;

        if (t > 0) {
            // every wave polls independently (no syncthreads on the sync path)
            if (lane < 16)
                while (__hip_atomic_load(&myflags[lane], __ATOMIC_RELAXED, __HIP_MEMORY_SCOPE_AGENT) < t)
                    __builtin_amdgcn_s_sleep(1);
            asm volatile("" ::: "memory");   // compiler barrier: h loads stay after poll
        }

        // h fragments direct from L3 (sc1): h[b][k], k = kt*32 + q*8 + j
        unsigned long long hb0[16][2], hb1[16][2];
        const unsigned long long* hp0 = (const unsigned long long*)(hprev + b0 * H_ + q * 8);
        const unsigned long long* hp1 = (const unsigned long long*)(hprev + b1 * H_ + q * 8);
        #pragma unroll
        for (int kt = 0; kt < 16; kt++) {
            hb0[kt][0] = ld_u64_dev(hp0 + kt * 8);
            hb0[kt][1] = ld_u64_dev(hp0 + kt * 8 + 1);
            hb1[kt][0] = ld_u64_dev(hp1 + kt * 8);
            hb1[kt][1] = ld_u64_dev(hp1 + kt * 8 + 1);
        }
        f32x4 acc00 = {}, acc01 = {}, acc10 = {}, acc11 = {};
        #pragma unroll
        for (int kt = 0; kt < 16; kt++) {
            union { unsigned long long u[2]; bf16x8 v; } h0, h1;
            h0.u[0] = hb0[kt][0]; h0.u[1] = hb0[kt][1];
            h1.u[0] = hb1[kt][0]; h1.u[1] = hb1[kt][1];
            acc00 = __builtin_amdgcn_mfma_f32_16x16x32_bf16(wr0[kt], h0.v, acc00, 0, 0, 0);
            acc01 = __builtin_amdgcn_mfma_f32_16x16x32_bf16(wr0[kt], h1.v, acc01, 0, 0, 0);
            acc10 = __builtin_amdgcn_mfma_f32_16x16x32_bf16(wr1[kt], h0.v, acc10, 0, 0, 0);
            acc11 = __builtin_amdgcn_mfma_f32_16x16x32_bf16(wr1[kt], h1.v, acc11, 0, 0, 0);
        }

        // gates fully in-register (r = gate: i,f,g,o)
        auto cell = [&](const f32x4& g, const bf16x4v& xv, float& c, float& h2, bool a) {
            float gi = g[0] + (float)xv[0];
            float gf = g[1] + (float)xv[1];
            float gg = g[2] + (float)xv[2];
            float go = g[3] + (float)xv[3];
            float cn = sigm(gf) * c + sigm(gi) * tanh_(gg);
            float hn = sigm(go) * tanh_(cn);
            if (a) { c = cn; h2 = hn; }    // alpha==0 freezes both (exact select)
        };
        cell(acc00, x00, c00, h00, a0);
        cell(acc01, x01, c01, h01, a1);
        cell(acc10, x10, c10, h10, a0);
        cell(acc11, x11, c11, h11, a1);

        bf16 v00 = (bf16)h00, v01 = (bf16)h01, v10 = (bf16)h10, v11 = (bf16)h11;
        st_b16_dev(hnext + b0 * H_ + u0,     v00);
        st_b16_dev(hnext + b1 * H_ + u0,     v01);
        st_b16_dev(hnext + b0 * H_ + u0 + 4, v10);
        st_b16_dev(hnext + b1 * H_ + u0 + 4, v11);
        size_t o0 = (size_t)(b0 * S_ + s) * H_, o1 = (size_t)(b1 * S_ + s) * H_;
        outp[o0 + u0] = v00;  outp[o1 + u0] = v01;
        outp[o0 + u0 + 4] = v10;  outp[o1 + u0 + 4] = v11;

        asm volatile("s_waitcnt vmcnt(0)" ::: "memory");  // sc1 stores acked at L3
        __syncthreads();                                   // all waves' stores done
        if (tid == 0)
            __hip_atomic_store(&flags[d * 64 + sl], t + 1, __ATOMIC_RELAXED, __HIP_MEMORY_SCOPE_AGENT);
    }
}

// ---------------- pooling ----------------
__launch_bounds__(256)
__global__ void k_pool(const bf16* __restrict__ outf, const bf16* __restrict__ outb,
                       const bf16* __restrict__ XG, const float* __restrict__ alphas,
                       float* __restrict__ out) {
    __shared__ float al[S_];
    int b = blockIdx.x;
    int j = blockIdx.y * 256 + threadIdx.x;     // 0..1023
    for (int i = threadIdx.x; i < S_; i += 256) al[i] = alphas[b * S_ + i];
    __syncthreads();
    int jj = (j < H_) ? j : j - H_;
    const bf16* tp = (j < H_) ? outf : outb;
    size_t base = (size_t)b * S_;
    float sum = 0.f, mx = -INFINITY, asum = 0.f;
    for (int s = 0; s < S_; s++) {
        float a = al[s]; asum += a;
        float r = (float)tp[(base + s) * H_ + jj] + (float)XG[(base + s) * NALL + 4096 + j];
        if (a > 0.f) { sum += r; mx = fmaxf(mx, r); }
    }
    float mean = sum / (asum + 1e-6f);
    if (mx == -INFINITY) mx = 0.f;
    out[b * 2048 + j] = mean;
    out[b * 2048 + 1024 + j] = mx;
}

extern "C" void kernel_launch(void* const* d_in, const int* in_sizes, int n_in,
                              void* d_out, int out_size, void* d_ws, size_t ws_size,
                              hipStream_t stream) {
    const float* values = (const float*)d_in[0];
    const float* alphas = (const float*)d_in[1];
    const float* Wx_f   = (const float*)d_in[2];
    const float* Wh_f   = (const float*)d_in[3];
    const float* b_f    = (const float*)d_in[4];
    const float* Wx_b   = (const float*)d_in[5];
    const float* Wh_b   = (const float*)d_in[6];
    const float* b_b    = (const float*)d_in[7];
    const float* Ws     = (const float*)d_in[8];
    const float* bs     = (const float*)d_in[9];
    float* out = (float*)d_out;

    char* ws = (char*)d_ws;
    size_t off = 0;
    auto alloc = [&](size_t bytes) { size_t p = off; off += (bytes + 255) & ~(size_t)255; return p; };
    bf16*  valsbf  = (bf16*)(ws + alloc((size_t)M_ * KV * 2));
    bf16*  wcat    = (bf16*)(ws + alloc((size_t)NALL * KV * 2));
    bf16*  whT     = (bf16*)(ws + alloc((size_t)4096 * H_ * 2));
    float* biascat = (float*)(ws + alloc((size_t)NALL * 4));
    bf16*  xg      = (bf16*)(ws + alloc((size_t)M_ * NALL * 2));
    bf16*  outfp   = (bf16*)(ws + alloc((size_t)M_ * H_ * 2));
    bf16*  outbp   = (bf16*)(ws + alloc((size_t)M_ * H_ * 2));
    bf16*  hex     = (bf16*)(ws + alloc((size_t)4 * 32 * H_ * 2));
    int*   flags   = (int*)(ws + alloc(128 * 4));
    unsigned int* abit = (unsigned int*)(ws + alloc(512 * 4));

    hipMemsetAsync(hex, 0, (size_t)4 * 32 * H_ * 2, stream);
    hipMemsetAsync(flags, 0, 128 * 4, stream);
    k_cvt_values<<<(M_ * KV) / (256 * 4), 256, 0, stream>>>(values, valsbf, M_ * KV);
    k_prep_abit<<<2, 256, 0, stream>>>(alphas, abit);
    k_prep_wcat<<<(NALL * 96) / 256, 256, 0, stream>>>(Wx_f, Wx_b, Ws, b_f, b_b, bs, wcat, biascat);
    k_prep_wh<<<(4096 * 64) / 256, 256, 0, stream>>>(Wh_f, Wh_b, whT);
    dim3 gg(M_ / BM, NALL / BN);
    k_gemm<<<gg, 256, 0, stream>>>(valsbf, wcat, biascat, xg);
    void* args[] = { (void*)&xg, (void*)&whT, (void*)&abit, (void*)&hex, (void*)&flags,
                     (void*)&outfp, (void*)&outbp };
    hipLaunchCooperativeKernel((void*)k_rnn, dim3(RWG), dim3(256), args, 0, stream);
    dim3 gp(B_, 1024 / 256);
    k_pool<<<gp, 256, 0, stream>>>(outfp, outbp, xg, alphas, out);
}

// Round 4
// 2571.125 us; speedup vs baseline: 2.2487x; 2.2487x over previous
//
#include <hip/hip_runtime.h>

#define B_   32
#define S_   512
#define V_   768
#define H_   512
#define M_   (B_*S_)      // 16384 rows
#define NALL 5120         // 2048 fwd gates | 2048 bwd gates | 1024 skip
#define KV   768
#define RWG  32           // recurrence workgroups (16 per direction)

typedef __bf16 bf16;
typedef __bf16 bf16x8 __attribute__((ext_vector_type(8)));
typedef __bf16 bf16x4v __attribute__((ext_vector_type(4)));
typedef float  f32x4  __attribute__((ext_vector_type(4)));

__device__ __forceinline__ float sigm(float x)  { return 1.0f / (1.0f + __expf(-x)); }
__device__ __forceinline__ float tanh_(float x) { return 1.0f - 2.0f / (__expf(2.0f*x) + 1.0f); }

// device-scope (L3-coherent) accesses: sc1 bypasses L1/L2 — no cache-wide fences
__device__ __forceinline__ uint4 ld_b128_sc1(const void* p) {
    uint4 v;
    asm volatile("global_load_dwordx4 %0, %1, off sc1" : "=v"(v) : "v"(p));
    return v;
}
__device__ __forceinline__ void st_b64_sc1(void* p, uint2 v) {
    asm volatile("global_store_dwordx2 %0, %1, off sc1" :: "v"(p), "v"(v));
}

// ---------------- prep: fp32 -> bf16 cast of values ----------------
__global__ void k_cvt_values(const float* __restrict__ v, bf16* __restrict__ o, int n) {
    int i = (blockIdx.x * blockDim.x + threadIdx.x) * 4;
    if (i < n) {
        float4 f = *(const float4*)(v + i);
        bf16x4v t;
        t[0] = (bf16)f.x; t[1] = (bf16)f.y; t[2] = (bf16)f.z; t[3] = (bf16)f.w;
        *(bf16x4v*)(o + i) = t;
    }
}

// ---------------- prep: alpha bitmask (alphas are exactly 0/1) ----------------
__global__ void k_prep_abit(const float* __restrict__ alphas, unsigned int* __restrict__ abit) {
    int i = blockIdx.x * blockDim.x + threadIdx.x;
    if (i >= 512) return;
    int b = i >> 4, w = i & 15;
    unsigned int m = 0;
    #pragma unroll
    for (int j = 0; j < 32; j++)
        if (alphas[b * S_ + w * 32 + j] != 0.f) m |= (1u << j);
    abit[b * 16 + w] = m;
}

// ---------------- prep: build transposed+interleaved weight cat ----------------
__global__ void k_prep_wcat(const float* __restrict__ Wx_f, const float* __restrict__ Wx_b,
                            const float* __restrict__ Ws,
                            const float* __restrict__ b_f, const float* __restrict__ b_b,
                            const float* __restrict__ bs,
                            bf16* __restrict__ wcat, float* __restrict__ biascat) {
    int idx = blockIdx.x * blockDim.x + threadIdx.x;
    int n = idx / 96, kc = idx % 96;
    if (n >= NALL) return;
    const float* src; int col, ldn;
    if (n < 4096) {
        int d = n >> 11, nl = n & 2047, unit = nl >> 2, gate = nl & 3;
        col = gate * H_ + unit; src = d ? Wx_b : Wx_f; ldn = 2048;
        if (kc == 0) biascat[n] = (d ? b_b : b_f)[col];
    } else {
        col = n - 4096; src = Ws; ldn = 1024;
        if (kc == 0) biascat[n] = bs[col];
    }
    int k0 = kc * 8;
    bf16x8 t;
    #pragma unroll
    for (int j = 0; j < 8; j++) t[j] = (bf16)src[(size_t)(k0 + j) * ldn + col];
    *(bf16x8*)(wcat + (size_t)n * KV + k0) = t;
}

// ---------------- prep: WhT (2 dirs x 2048 rows x 512 k), same interleave ----------------
__global__ void k_prep_wh(const float* __restrict__ Wh_f, const float* __restrict__ Wh_b,
                          bf16* __restrict__ whT) {
    int idx = blockIdx.x * blockDim.x + threadIdx.x;
    int n = idx >> 6, kc = idx & 63;
    if (n >= 4096) return;
    int d = n >> 11, nl = n & 2047, unit = nl >> 2, gate = nl & 3;
    int col = gate * H_ + unit;
    const float* src = d ? Wh_b : Wh_f;
    int k0 = kc * 8;
    bf16x8 t;
    #pragma unroll
    for (int j = 0; j < 8; j++) t[j] = (bf16)src[(size_t)(k0 + j) * 2048 + col];
    *(bf16x8*)(whT + (size_t)n * H_ + k0) = t;
}

// ---------------- big GEMM: XG[16384 x 5120] = vals_bf16 @ wcat^T + bias ----------------
#define BM 64
#define BN 64
#define BK 32
#define LDT 40

__launch_bounds__(256)
__global__ void k_gemm(const bf16* __restrict__ A, const bf16* __restrict__ Bw,
                       const float* __restrict__ bias, bf16* __restrict__ C) {
    __shared__ bf16 As[BM * LDT];
    __shared__ bf16 Bs[BN * LDT];
    int m0 = blockIdx.x * BM, n0 = blockIdx.y * BN;
    int tid = threadIdx.x;
    int wv = tid >> 6, lane = tid & 63, lm = lane & 15, q = lane >> 4;
    int wm = (wv >> 1) * 32, wn = (wv & 1) * 32;
    f32x4 acc[2][2] = {};
    int lr = tid >> 2, lc = (tid & 3) * 8;
    const bf16* Ag = A  + (size_t)(m0 + lr) * KV + lc;
    const bf16* Bg = Bw + (size_t)(n0 + lr) * KV + lc;
    for (int kb = 0; kb < KV; kb += BK) {
        *(bf16x8*)&As[lr * LDT + lc] = *(const bf16x8*)(Ag + kb);
        *(bf16x8*)&Bs[lr * LDT + lc] = *(const bf16x8*)(Bg + kb);
        __syncthreads();
        bf16x8 af[2], bfr[2];
        af[0]  = *(bf16x8*)&As[(wm      + lm) * LDT + q * 8];
        af[1]  = *(bf16x8*)&As[(wm + 16 + lm) * LDT + q * 8];
        bfr[0] = *(bf16x8*)&Bs[(wn      + lm) * LDT + q * 8];
        bfr[1] = *(bf16x8*)&Bs[(wn + 16 + lm) * LDT + q * 8];
        #pragma unroll
        for (int mt = 0; mt < 2; mt++)
            #pragma unroll
            for (int nt = 0; nt < 2; nt++)
                acc[mt][nt] = __builtin_amdgcn_mfma_f32_16x16x32_bf16(af[mt], bfr[nt], acc[mt][nt], 0, 0, 0);
        __syncthreads();
    }
    #pragma unroll
    for (int mt = 0; mt < 2; mt++)
        #pragma unroll
        for (int nt = 0; nt < 2; nt++) {
            int col = n0 + wn + nt * 16 + lm;
            float bv = bias[col];
            #pragma unroll
            for (int r = 0; r < 4; r++) {
                int row = m0 + wm + mt * 16 + q * 4 + r;
                C[(size_t)row * NALL + col] = (bf16)(acc[mt][nt][r] + bv);
            }
        }
}

// ---------------- recurrence: transposed MFMA + coalesced sc1 exchange ----------------
// 32 WGs: d=wg>>4, sl=wg&15 owns units [sl*32, sl*32+32) (128 gate cols).
// MFMA A = Wh rows (gate cols), B = h rows (batches): lane's 4 acc regs = the 4
// gates of one (unit,batch); c,h2 persist in registers. h exchange:
//   consume: coalesced 16B sc1 loads -> LDS -> ds_read_b128 fragments
//   publish: gather 2KB slice in LDS -> coalesced 8B sc1 stores (full lines)
// Ordering: s_waitcnt vmcnt(0) + barrier + relaxed agent flag. No cache fences.
__launch_bounds__(256, 1)
__global__ void k_rnn(const bf16* __restrict__ XG, const bf16* __restrict__ WhT,
                      const unsigned int* __restrict__ abit,
                      bf16* __restrict__ hex, int* __restrict__ flags,
                      bf16* __restrict__ outf, bf16* __restrict__ outb) {
    __shared__ __align__(16) char hsb[32 * 1040];   // h staging: 32 rows x 520 elems
    __shared__ __align__(8)  char houtb[32 * 72];   // h2 gather: 32 rows x 32 units (+pad)
    __shared__ unsigned int ab[32 * 16];

    int wg = blockIdx.x;
    int d = wg >> 4, sl = wg & 15;
    int tid = threadIdx.x;
    int wv = tid >> 6, lane = tid & 63, lm = lane & 15, q = lane >> 4;
    bf16* outp = d ? outb : outf;
    int* myflags = flags + d * 64;

    for (int i = tid; i < 512; i += 256) ab[i] = abit[i];

    // Wh A-fragments: rows d*2048+sl*128+wv*32+{0,16}+lm, k-contig
    const bf16* wb = WhT + (size_t)(d * 2048 + sl * 128 + wv * 32 + lm) * H_ + q * 8;
    bf16x8 wr0[16], wr1[16];
    #pragma unroll
    for (int kt = 0; kt < 16; kt++) {
        wr0[kt] = *(const bf16x8*)(wb + kt * 32);
        wr1[kt] = *(const bf16x8*)(wb + (size_t)16 * H_ + kt * 32);
    }
    __syncthreads();

    int b0 = lm, b1 = 16 + lm;
    int ul0 = wv * 8 + q;               // unit_local for mt=0; mt=1 is ul0+4
    int u0  = sl * 32 + ul0;
    int xcb = d * 2048 + sl * 128 + wv * 32 + q * 4;
    int sb = tid >> 3, sc = tid & 7;    // publish mapping: batch, 8B chunk
    float c00 = 0.f, c01 = 0.f, c10 = 0.f, c11 = 0.f;
    float h00 = 0.f, h01 = 0.f, h10 = 0.f, h11 = 0.f;

    for (int t = 0; t < S_; t++) {
        int s = d ? (S_ - 1 - t) : t;
        const char* hprev = (const char*)(hex + (size_t)(d * 2 + (t & 1)) * (32 * H_));
        char*       hnext = (char*)(hex + (size_t)(d * 2 + ((t + 1) & 1)) * (32 * H_));

        // prefetch xg + alpha bits (independent of h) before the poll
        size_t r0 = (size_t)(b0 * S_ + s) * NALL + xcb;
        size_t r1 = (size_t)(b1 * S_ + s) * NALL + xcb;
        bf16x4v x00 = *(const bf16x4v*)(XG + r0);
        bf16x4v x01 = *(const bf16x4v*)(XG + r1);
        bf16x4v x10 = *(const bf16x4v*)(XG + r0 + 16);
        bf16x4v x11 = *(const bf16x4v*)(XG + r1 + 16);
        bool a0 = (ab[b0 * 16 + (s >> 5)] >> (s & 31)) & 1;
        bool a1 = (ab[b1 * 16 + (s >> 5)] >> (s & 31)) & 1;

        if (t > 0) {
            if (lane < 16)
                while (__hip_atomic_load(&myflags[lane], __ATOMIC_RELAXED, __HIP_MEMORY_SCOPE_AGENT) < t)
                    __builtin_amdgcn_s_sleep(1);
            asm volatile("" ::: "memory");
        }

        // stage h (32KB) into LDS: coalesced 16B sc1 loads, 8 per thread
        uint4 hv[8];
        #pragma unroll
        for (int j = 0; j < 8; j++) {
            int c = tid + j * 256;
            hv[j] = ld_b128_sc1(hprev + (c >> 6) * 1024 + (c & 63) * 16);
        }
        asm volatile("s_waitcnt vmcnt(0)" ::: "memory");
        #pragma unroll
        for (int j = 0; j < 8; j++) {
            int c = tid + j * 256;
            *(uint4*)(hsb + (c >> 6) * 1040 + (c & 63) * 16) = hv[j];
        }
        __syncthreads();

        f32x4 acc00 = {}, acc01 = {}, acc10 = {}, acc11 = {};
        #pragma unroll
        for (int kt = 0; kt < 16; kt++) {
            bf16x8 h0 = *(const bf16x8*)(hsb + b0 * 1040 + kt * 64 + q * 16);
            bf16x8 h1 = *(const bf16x8*)(hsb + b1 * 1040 + kt * 64 + q * 16);
            acc00 = __builtin_amdgcn_mfma_f32_16x16x32_bf16(wr0[kt], h0, acc00, 0, 0, 0);
            acc01 = __builtin_amdgcn_mfma_f32_16x16x32_bf16(wr0[kt], h1, acc01, 0, 0, 0);
            acc10 = __builtin_amdgcn_mfma_f32_16x16x32_bf16(wr1[kt], h0, acc10, 0, 0, 0);
            acc11 = __builtin_amdgcn_mfma_f32_16x16x32_bf16(wr1[kt], h1, acc11, 0, 0, 0);
        }

        auto cell = [&](const f32x4& g, const bf16x4v& xv, float& c, float& h2, bool a) {
            float gi = g[0] + (float)xv[0];
            float gf = g[1] + (float)xv[1];
            float gg = g[2] + (float)xv[2];
            float go = g[3] + (float)xv[3];
            float cn = sigm(gf) * c + sigm(gi) * tanh_(gg);
            float hn = sigm(go) * tanh_(cn);
            if (a) { c = cn; h2 = hn; }    // alpha==0 freezes both (exact select)
        };
        cell(acc00, x00, c00, h00, a0);
        cell(acc01, x01, c01, h01, a1);
        cell(acc10, x10, c10, h10, a0);
        cell(acc11, x11, c11, h11, a1);

        // gather h2 slice (2KB) in LDS for coalesced publish
        *(unsigned short*)(houtb + b0 * 72 + ul0 * 2)       = __builtin_bit_cast(unsigned short, (bf16)h00);
        *(unsigned short*)(houtb + b1 * 72 + ul0 * 2)       = __builtin_bit_cast(unsigned short, (bf16)h01);
        *(unsigned short*)(houtb + b0 * 72 + (ul0 + 4) * 2) = __builtin_bit_cast(unsigned short, (bf16)h10);
        *(unsigned short*)(houtb + b1 * 72 + (ul0 + 4) * 2) = __builtin_bit_cast(unsigned short, (bf16)h11);
        __syncthreads();

        uint2 hv2 = *(const uint2*)(houtb + sb * 72 + sc * 8);
        st_b64_sc1(hnext + sb * 1024 + sl * 64 + sc * 8, hv2);
        *(uint2*)((char*)outp + ((size_t)(sb * S_ + s) * H_ + sl * 32) * 2 + sc * 8) = hv2;

        asm volatile("s_waitcnt vmcnt(0)" ::: "memory");
        __syncthreads();
        if (tid == 0)
            __hip_atomic_store(&flags[d * 64 + sl], t + 1, __ATOMIC_RELAXED, __HIP_MEMORY_SCOPE_AGENT);
    }
}

// ---------------- pooling ----------------
__launch_bounds__(256)
__global__ void k_pool(const bf16* __restrict__ outf, const bf16* __restrict__ outb,
                       const bf16* __restrict__ XG, const float* __restrict__ alphas,
                       float* __restrict__ out) {
    __shared__ float al[S_];
    int b = blockIdx.x;
    int j = blockIdx.y * 256 + threadIdx.x;
    for (int i = threadIdx.x; i < S_; i += 256) al[i] = alphas[b * S_ + i];
    __syncthreads();
    int jj = (j < H_) ? j : j - H_;
    const bf16* tp = (j < H_) ? outf : outb;
    size_t base = (size_t)b * S_;
    float sum = 0.f, mx = -INFINITY, asum = 0.f;
    for (int s = 0; s < S_; s++) {
        float a = al[s]; asum += a;
        float r = (float)tp[(base + s) * H_ + jj] + (float)XG[(base + s) * NALL + 4096 + j];
        if (a > 0.f) { sum += r; mx = fmaxf(mx, r); }
    }
    float mean = sum / (asum + 1e-6f);
    if (mx == -INFINITY) mx = 0.f;
    out[b * 2048 + j] = mean;
    out[b * 2048 + 1024 + j] = mx;
}

extern "C" void kernel_launch(void* const* d_in, const int* in_sizes, int n_in,
                              void* d_out, int out_size, void* d_ws, size_t ws_size,
                              hipStream_t stream) {
    const float* values = (const float*)d_in[0];
    const float* alphas = (const float*)d_in[1];
    const float* Wx_f   = (const float*)d_in[2];
    const float* Wh_f   = (const float*)d_in[3];
    const float* b_f    = (const float*)d_in[4];
    const float* Wx_b   = (const float*)d_in[5];
    const float* Wh_b   = (const float*)d_in[6];
    const float* b_b    = (const float*)d_in[7];
    const float* Ws     = (const float*)d_in[8];
    const float* bs     = (const float*)d_in[9];
    float* out = (float*)d_out;

    char* ws = (char*)d_ws;
    size_t off = 0;
    auto alloc = [&](size_t bytes) { size_t p = off; off += (bytes + 255) & ~(size_t)255; return p; };
    bf16*  valsbf  = (bf16*)(ws + alloc((size_t)M_ * KV * 2));
    bf16*  wcat    = (bf16*)(ws + alloc((size_t)NALL * KV * 2));
    bf16*  whT     = (bf16*)(ws + alloc((size_t)4096 * H_ * 2));
    float* biascat = (float*)(ws + alloc((size_t)NALL * 4));
    bf16*  xg      = (bf16*)(ws + alloc((size_t)M_ * NALL * 2));
    bf16*  outfp   = (bf16*)(ws + alloc((size_t)M_ * H_ * 2));
    bf16*  outbp   = (bf16*)(ws + alloc((size_t)M_ * H_ * 2));
    bf16*  hex     = (bf16*)(ws + alloc((size_t)4 * 32 * H_ * 2));
    int*   flags   = (int*)(ws + alloc(128 * 4));
    unsigned int* abit = (unsigned int*)(ws + alloc(512 * 4));

    hipMemsetAsync(hex, 0, (size_t)4 * 32 * H_ * 2, stream);
    hipMemsetAsync(flags, 0, 128 * 4, stream);
    k_cvt_values<<<(M_ * KV) / (256 * 4), 256, 0, stream>>>(values, valsbf, M_ * KV);
    k_prep_abit<<<2, 256, 0, stream>>>(alphas, abit);
    k_prep_wcat<<<(NALL * 96) / 256, 256, 0, stream>>>(Wx_f, Wx_b, Ws, b_f, b_b, bs, wcat, biascat);
    k_prep_wh<<<(4096 * 64) / 256, 256, 0, stream>>>(Wh_f, Wh_b, whT);
    dim3 gg(M_ / BM, NALL / BN);
    k_gemm<<<gg, 256, 0, stream>>>(valsbf, wcat, biascat, xg);
    void* args[] = { (void*)&xg, (void*)&whT, (void*)&abit, (void*)&hex, (void*)&flags,
                     (void*)&outfp, (void*)&outbp };
    hipLaunchCooperativeKernel((void*)k_rnn, dim3(RWG), dim3(256), args, 0, stream);
    dim3 gp(B_, 1024 / 256);
    k_pool<<<gp, 256, 0, stream>>>(outfp, outbp, xg, alphas, out);
}